// Round 10
// baseline (748.409 us; speedup 1.0000x reference)
//
#include <hip/hip_runtime.h>
#include <hip/hip_cooperative_groups.h>

namespace cg = cooperative_groups;

typedef unsigned short u16;
typedef unsigned int u32;
typedef __bf16 bf16x8 __attribute__((ext_vector_type(8)));
typedef float f32x4 __attribute__((ext_vector_type(4)));
typedef u32 u32x2 __attribute__((ext_vector_type(2)));
typedef u32 u32x4 __attribute__((ext_vector_type(4)));

#define M_DIM 8192
#define CCH 512              /* conv staging chunk (k-cols) */
#define NCH (M_DIM / CCH)    /* 16 chunks */

__device__ __forceinline__ u16 f2bf(float f) {
  return __builtin_bit_cast(u16, (__bf16)f);  // HW RNE cvt
}

union Frag {
  bf16x8 f;
  u16 s[8];
  u32x2 h2[2];
  u32x4 q;
};

// zbt layout: ((kt*2 + nt)*64 + lane)*8 + j holds z[k = kt*32 + 8*(lane>>4)+j]
//                                                 [n = nt*16 + (lane&15)]
// Lbt layout: ((rt*256 + ktile)*512) + lane*8 + j holds
//             L[m = rt*16+(lane&15)][k = ktile*32 + 8*(lane>>4) + j]

// ============================ mega (cooperative) ============================
__global__ __launch_bounds__(512, 4) void mega_kernel(
    const float* __restrict__ x, const float* __restrict__ L,
    const float* __restrict__ W, float* __restrict__ y,
    u16* __restrict__ Lbt, u16* __restrict__ zbtA, u16* __restrict__ zbtB) {
  __shared__ u16 At[2][16][520];
  __shared__ float red[8][16][33];
  __shared__ float Ws[1024];
  __shared__ float zs[16][33];
  __shared__ u16 zsb[16][36];
  __shared__ float yac[16][32];

  cg::grid_group grid = cg::this_grid();

  const int t = threadIdx.x;
  const int lane = t & 63, w = t >> 6;
  const int l15 = lane & 15, l4 = lane >> 4;
  const int bx = blockIdx.x;       // [0,512)
  const int r0 = bx * 16;
  const int row = t >> 5, j = t & 31;

  // P0: head — yac = x@W0 ; emit zbt0 = frag(bf16(x)) -> zbtA
  for (int i = t; i < 1024; i += 512) Ws[i] = W[i];
  {
    float xv = x[(size_t)(r0 + row) * 32 + j];
    zs[row][j] = xv;
    zsb[row][j] = f2bf(xv);
  }
  __syncthreads();
  {
    float a = 0.f;
#pragma unroll
    for (int c = 0; c < 32; c++) a += zs[row][c] * Ws[c * 32 + j];
    yac[row][j] = a;
  }
  if (t < 64) {
    const int nt = t >> 5, li = t & 31;
    const int kt = bx >> 1, h = bx & 1;
    Frag fr;
#pragma unroll
    for (int jj = 0; jj < 8; jj++)
      fr.s[jj] = zsb[8 * (li >> 4) + jj][nt * 16 + (li & 15)];
    *(u32x4*)(zbtA + (size_t)((kt * 2 + nt) * 64 + 32 * h + li) * 8) = fr.q;
  }
  __threadfence();
  grid.sync();

  // P1: conv — L -> Lbt ; z1 = L@z0 ; yac += z1@W1 ; emit -> zbtB
  for (int i = t; i < 1024; i += 512) Ws[i] = W[1024 + i];
  {
    const float* sbase = L + (size_t)(r0 + row) * M_DIM + j * 4;

    auto stage = [&](int c, int buf) {
      const float* src = sbase + c * CCH;
      u16* dst = &At[buf][row][j * 4];
#pragma unroll
      for (int seg = 0; seg < 4; seg++) {
        f32x4 v = __builtin_nontemporal_load((const f32x4*)(src + seg * 128));
        u32x2 p;
        p[0] = (u32)f2bf(v[0]) | ((u32)f2bf(v[1]) << 16);
        p[1] = (u32)f2bf(v[2]) | ((u32)f2bf(v[3]) << 16);
        *(u32x2*)(dst + seg * 128) = p;
      }
    };

    f32x4 acc0 = {0.f, 0.f, 0.f, 0.f};
    f32x4 acc1 = {0.f, 0.f, 0.f, 0.f};

    stage(0, 0);
    int buf = 0;
    for (int c = 0; c < NCH; c++) {
      __syncthreads();
      if (c + 1 < NCH) stage(c + 1, buf ^ 1);
#pragma unroll
      for (int i = 0; i < 2; i++) {
        const int ktl = c * 16 + w * 2 + i;
        Frag fa;
        fa.q = *(const u32x4*)&At[buf][l15][(w * 2 + i) * 32 + 8 * l4];
        *(u32x4*)(Lbt + ((size_t)bx * 256 + ktl) * 512 + lane * 8) = fa.q;
        Frag fb0, fb1;
        size_t bo = ((size_t)ktl * 2) * 512 + lane * 8;
        fb0.q = *(const u32x4*)(zbtA + bo);
        fb1.q = *(const u32x4*)(zbtA + bo + 512);
        acc0 = __builtin_amdgcn_mfma_f32_16x16x32_bf16(fa.f, fb0.f, acc0, 0, 0, 0);
        acc1 = __builtin_amdgcn_mfma_f32_16x16x32_bf16(fa.f, fb1.f, acc1, 0, 0, 0);
      }
      buf ^= 1;
    }

#pragma unroll
    for (int r = 0; r < 4; r++) {
      red[w][4 * l4 + r][l15] = acc0[r];
      red[w][4 * l4 + r][l15 + 16] = acc1[r];
    }
    __syncthreads();
    float v = 0.f;
#pragma unroll
    for (int s = 0; s < 8; s++) v += red[s][row][j];
    zs[row][j] = v;
    zsb[row][j] = f2bf(v);
    __syncthreads();
    float a = yac[row][j];
#pragma unroll
    for (int c = 0; c < 32; c++) a += zs[row][c] * Ws[c * 32 + j];
    yac[row][j] = a;
    if (t < 64) {
      const int nt = t >> 5, li = t & 31;
      const int kt = bx >> 1, h = bx & 1;
      Frag fr;
#pragma unroll
      for (int jj = 0; jj < 8; jj++)
        fr.s[jj] = zsb[8 * (li >> 4) + jj][nt * 16 + (li & 15)];
      *(u32x4*)(zbtB + (size_t)((kt * 2 + nt) * 64 + 32 * h + li) * 8) = fr.q;
    }
  }
  __threadfence();
  grid.sync();

  // P2..P4: fpass x3 (Lbt slice rt=bx is block-private)
  auto fpass = [&](const u16* zin, u16* zout, const float* Wk, float* ygout) {
    for (int i = t; i < 1024; i += 512) Ws[i] = Wk[i];
    const u16* ap = Lbt + ((size_t)bx * 256 + w * 32) * 512 + lane * 8;
    const u16* bp = zin + (size_t)(w * 32) * 1024 + lane * 8;

    f32x4 acc0 = {0.f, 0.f, 0.f, 0.f};
    f32x4 acc1 = {0.f, 0.f, 0.f, 0.f};
#pragma unroll 8
    for (int kt = 0; kt < 32; kt++) {
      Frag fa, fb0, fb1;
      fa.q = *(const u32x4*)(ap + (size_t)kt * 512);
      fb0.q = *(const u32x4*)(bp + (size_t)kt * 1024);
      fb1.q = *(const u32x4*)(bp + (size_t)kt * 1024 + 512);
      acc0 = __builtin_amdgcn_mfma_f32_16x16x32_bf16(fa.f, fb0.f, acc0, 0, 0, 0);
      acc1 = __builtin_amdgcn_mfma_f32_16x16x32_bf16(fa.f, fb1.f, acc1, 0, 0, 0);
    }
#pragma unroll
    for (int r = 0; r < 4; r++) {
      red[w][4 * l4 + r][l15] = acc0[r];
      red[w][4 * l4 + r][l15 + 16] = acc1[r];
    }
    __syncthreads();
    float v = 0.f;
#pragma unroll
    for (int s = 0; s < 8; s++) v += red[s][row][j];
    zs[row][j] = v;
    zsb[row][j] = f2bf(v);
    __syncthreads();
    float a = yac[row][j];
#pragma unroll
    for (int c = 0; c < 32; c++) a += zs[row][c] * Ws[c * 32 + j];
    if (ygout) {
      ygout[(size_t)(r0 + row) * 32 + j] = a;
    } else {
      yac[row][j] = a;
      if (t < 64) {
        const int nt = t >> 5, li = t & 31;
        const int kt = bx >> 1, h = bx & 1;
        Frag fr;
#pragma unroll
        for (int jj = 0; jj < 8; jj++)
          fr.s[jj] = zsb[8 * (li >> 4) + jj][nt * 16 + (li & 15)];
        *(u32x4*)(zout + (size_t)((kt * 2 + nt) * 64 + 32 * h + li) * 8) = fr.q;
      }
    }
  };

  fpass(zbtB, zbtA, W + 2048, (float*)0);
  __threadfence();
  grid.sync();
  fpass(zbtA, zbtB, W + 3072, (float*)0);
  __threadfence();
  grid.sync();
  fpass(zbtB, (u16*)0, W + 4096, y);
}

// ===================== fallback: round-5 proven pipeline ====================
__global__ __launch_bounds__(256) void head_kernel(
    const float* __restrict__ x, const float* __restrict__ W0,
    float* __restrict__ y_out, u16* __restrict__ zbt0) {
  __shared__ float Ws[1024];
  __shared__ u16 zsb[256][34];
  const int t = threadIdx.x;
  for (int i = t; i < 1024; i += 256) Ws[i] = W0[i];
  const int m = blockIdx.x * 256 + t;
  float z[32];
  const float4* xr = (const float4*)(x + (size_t)m * 32);
#pragma unroll
  for (int i = 0; i < 8; i++) {
    float4 v = xr[i];
    z[4 * i] = v.x; z[4 * i + 1] = v.y; z[4 * i + 2] = v.z; z[4 * i + 3] = v.w;
  }
#pragma unroll
  for (int c = 0; c < 32; c++) zsb[t][c] = f2bf(z[c]);
  __syncthreads();
  float acc[32];
#pragma unroll
  for (int j = 0; j < 32; j++) acc[j] = 0.f;
#pragma unroll
  for (int c = 0; c < 32; c++) {
#pragma unroll
    for (int j = 0; j < 32; j++) acc[j] += z[c] * Ws[c * 32 + j];
  }
  float4* yo = (float4*)(y_out + (size_t)m * 32);
#pragma unroll
  for (int i = 0; i < 8; i++) {
    float4 v; v.x = acc[4 * i]; v.y = acc[4 * i + 1];
    v.z = acc[4 * i + 2]; v.w = acc[4 * i + 3];
    yo[i] = v;
  }
  const int lane = t & 63, w = t >> 6;
  const int l15 = lane & 15, l4 = lane >> 4;
#pragma unroll
  for (int i = 0; i < 4; i++) {
    int tile = w * 4 + i;
    int ktl = tile >> 1, nt = tile & 1;
    Frag fr;
#pragma unroll
    for (int j = 0; j < 8; j++) fr.s[j] = zsb[ktl * 32 + 8 * l4 + j][nt * 16 + l15];
    size_t kt_g = (size_t)blockIdx.x * 8 + ktl;
    *(u32x4*)(zbt0 + ((kt_g * 2 + nt) * 64 + lane) * 8) = fr.q;
  }
}

__global__ __launch_bounds__(512, 4) void conv_kernel(
    const float* __restrict__ L, const u16* __restrict__ zbt0,
    const float* __restrict__ W1, const float* __restrict__ y_in,
    float* __restrict__ y_out, u16* __restrict__ Lbt,
    u16* __restrict__ zbt_out) {
  __shared__ u16 At[2][16][520];
  __shared__ float red[8][16][33];
  __shared__ float Ws[1024];
  __shared__ float zs[16][33];
  __shared__ u16 zsb[16][36];
  const int t = threadIdx.x;
  const int lane = t & 63, w = t >> 6;
  const int l15 = lane & 15, l4 = lane >> 4;
  const int bx = blockIdx.x;
  const int r0 = bx * 16;
  for (int i = t; i < 1024; i += 512) Ws[i] = W1[i];

  const int srow = t >> 5, scg = t & 31;
  const float* sbase = L + (size_t)(r0 + srow) * M_DIM + scg * 4;

  auto stage = [&](int c, int buf) {
    const float* src = sbase + c * CCH;
    u16* dst = &At[buf][srow][scg * 4];
#pragma unroll
    for (int seg = 0; seg < 4; seg++) {
      f32x4 v = __builtin_nontemporal_load((const f32x4*)(src + seg * 128));
      u32x2 p;
      p[0] = (u32)f2bf(v[0]) | ((u32)f2bf(v[1]) << 16);
      p[1] = (u32)f2bf(v[2]) | ((u32)f2bf(v[3]) << 16);
      *(u32x2*)(dst + seg * 128) = p;
    }
  };

  f32x4 acc0 = {0.f, 0.f, 0.f, 0.f};
  f32x4 acc1 = {0.f, 0.f, 0.f, 0.f};

  stage(0, 0);
  int buf = 0;
  for (int c = 0; c < NCH; c++) {
    __syncthreads();
    if (c + 1 < NCH) stage(c + 1, buf ^ 1);
#pragma unroll
    for (int i = 0; i < 2; i++) {
      const int ktl = c * 16 + w * 2 + i;
      Frag fa;
      fa.q = *(const u32x4*)&At[buf][l15][(w * 2 + i) * 32 + 8 * l4];
      *(u32x4*)(Lbt + ((size_t)bx * 256 + ktl) * 512 + lane * 8) = fa.q;
      Frag fb0, fb1;
      size_t bo = ((size_t)ktl * 2) * 512 + lane * 8;
      fb0.q = *(const u32x4*)(zbt0 + bo);
      fb1.q = *(const u32x4*)(zbt0 + bo + 512);
      acc0 = __builtin_amdgcn_mfma_f32_16x16x32_bf16(fa.f, fb0.f, acc0, 0, 0, 0);
      acc1 = __builtin_amdgcn_mfma_f32_16x16x32_bf16(fa.f, fb1.f, acc1, 0, 0, 0);
    }
    buf ^= 1;
  }

#pragma unroll
  for (int r = 0; r < 4; r++) {
    red[w][4 * l4 + r][l15] = acc0[r];
    red[w][4 * l4 + r][l15 + 16] = acc1[r];
  }
  __syncthreads();
  const int row = t >> 5, j = t & 31;
  float v = 0.f;
#pragma unroll
  for (int s = 0; s < 8; s++) v += red[s][row][j];
  zs[row][j] = v;
  zsb[row][j] = f2bf(v);
  __syncthreads();
  float yv = y_in[(size_t)(r0 + row) * 32 + j];
#pragma unroll
  for (int c = 0; c < 32; c++) yv += zs[row][c] * Ws[c * 32 + j];
  y_out[(size_t)(r0 + row) * 32 + j] = yv;

  if (t < 64) {
    const int nt = t >> 5, li = t & 31;
    const int kt = bx >> 1, h = bx & 1;
    Frag fr;
#pragma unroll
    for (int jj = 0; jj < 8; jj++)
      fr.s[jj] = zsb[8 * (li >> 4) + jj][nt * 16 + (li & 15)];
    *(u32x4*)(zbt_out + (size_t)((kt * 2 + nt) * 64 + 32 * h + li) * 8) = fr.q;
  }
}

template <bool LAST>
__global__ __launch_bounds__(512, 4) void fpass_kernel(
    const u16* __restrict__ Lbt, const u16* __restrict__ zbt,
    const float* __restrict__ Wk, const float* __restrict__ y_in,
    float* __restrict__ y_out, u16* __restrict__ zbt_out) {
  __shared__ float red[8][16][33];
  __shared__ float Ws[1024];
  __shared__ float zs[16][33];
  __shared__ u16 zsb[16][36];
  const int t = threadIdx.x;
  const int lane = t & 63, w = t >> 6;
  const int l15 = lane & 15, l4 = lane >> 4;
  const int bx = blockIdx.x;
  for (int i = t; i < 1024; i += 512) Ws[i] = Wk[i];

  const u16* ap = Lbt + ((size_t)bx * 256 + w * 32) * 512 + lane * 8;
  const u16* bp = zbt + (size_t)(w * 32) * 1024 + lane * 8;

  f32x4 acc0 = {0.f, 0.f, 0.f, 0.f};
  f32x4 acc1 = {0.f, 0.f, 0.f, 0.f};
#pragma unroll 8
  for (int kt = 0; kt < 32; kt++) {
    Frag fa, fb0, fb1;
    fa.q = *(const u32x4*)(ap + (size_t)kt * 512);
    fb0.q = *(const u32x4*)(bp + (size_t)kt * 1024);
    fb1.q = *(const u32x4*)(bp + (size_t)kt * 1024 + 512);
    acc0 = __builtin_amdgcn_mfma_f32_16x16x32_bf16(fa.f, fb0.f, acc0, 0, 0, 0);
    acc1 = __builtin_amdgcn_mfma_f32_16x16x32_bf16(fa.f, fb1.f, acc1, 0, 0, 0);
  }
#pragma unroll
  for (int r = 0; r < 4; r++) {
    red[w][4 * l4 + r][l15] = acc0[r];
    red[w][4 * l4 + r][l15 + 16] = acc1[r];
  }
  __syncthreads();
  const int row = t >> 5, j = t & 31;
  float v = 0.f;
#pragma unroll
  for (int s = 0; s < 8; s++) v += red[s][row][j];
  zs[row][j] = v;
  zsb[row][j] = f2bf(v);
  __syncthreads();
  float yv = y_in[(size_t)(bx * 16 + row) * 32 + j];
#pragma unroll
  for (int c = 0; c < 32; c++) yv += zs[row][c] * Ws[c * 32 + j];
  y_out[(size_t)(bx * 16 + row) * 32 + j] = yv;

  if (!LAST && t < 64) {
    const int nt = t >> 5, li = t & 31;
    const int kt = bx >> 1, h = bx & 1;
    Frag fr;
#pragma unroll
    for (int jj = 0; jj < 8; jj++)
      fr.s[jj] = zsb[8 * (li >> 4) + jj][nt * 16 + (li & 15)];
    *(u32x4*)(zbt_out + (size_t)((kt * 2 + nt) * 64 + 32 * h + li) * 8) = fr.q;
  }
}

extern "C" void kernel_launch(void* const* d_in, const int* in_sizes, int n_in,
                              void* d_out, int out_size, void* d_ws,
                              size_t ws_size, hipStream_t stream) {
  const float* x = (const float*)d_in[0];
  const float* L = (const float*)d_in[1];
  const float* W = (const float*)d_in[2];
  float* y = (float*)d_out;
  char* ws = (char*)d_ws;

  const size_t ZT = (size_t)512 << 10;        // 512 KB per zbt
  u16* zbt0 = (u16*)(ws + 0 * ZT);
  u16* zbt1 = (u16*)(ws + 1 * ZT);
  u16* zbt2 = (u16*)(ws + 2 * ZT);
  u16* zbt3 = (u16*)(ws + 3 * ZT);
  float* y_acc = (float*)(ws + ((size_t)10 << 20));  // 1 MB @ 10 MiB
  u16* Lbt = (u16*)(ws + ((size_t)12 << 20));        // 128 MiB @ 12 MiB

  // Try the cooperative mega-kernel; on any launch rejection fall back to the
  // proven 5-kernel pipeline. The branch outcome is fixed per environment, so
  // work is deterministic across calls and identical under graph capture.
  void* args[] = {(void*)&x, (void*)&L, (void*)&W, (void*)&y,
                  (void*)&Lbt, (void*)&zbt0, (void*)&zbt1};
  hipError_t err = hipLaunchCooperativeKernel((void*)mega_kernel, dim3(512),
                                              dim3(512), args, 0, stream);
  if (err != hipSuccess) {
    (void)hipGetLastError();  // clear sticky error state
    head_kernel<<<32, 256, 0, stream>>>(x, W, y_acc, zbt0);
    conv_kernel<<<512, 512, 0, stream>>>(L, zbt0, W + 1024, y_acc, y_acc, Lbt, zbt1);
    fpass_kernel<false><<<512, 512, 0, stream>>>(Lbt, zbt1, W + 2048, y_acc, y_acc, zbt2);
    fpass_kernel<false><<<512, 512, 0, stream>>>(Lbt, zbt2, W + 3072, y_acc, y_acc, zbt3);
    fpass_kernel<true><<<512, 512, 0, stream>>>(Lbt, zbt3, W + 4096, y_acc, y, (u16*)0);
  }
}

// Round 11
// 176.430 us; speedup vs baseline: 4.2420x; 4.2420x over previous
//
#include <hip/hip_runtime.h>

typedef unsigned short u16;
typedef unsigned int u32;
typedef __bf16 bf16x8 __attribute__((ext_vector_type(8)));
typedef float f32x4 __attribute__((ext_vector_type(4)));
typedef u32 u32x2 __attribute__((ext_vector_type(2)));
typedef u32 u32x4 __attribute__((ext_vector_type(4)));

#define M_DIM 8192
#define CCH 256              /* conv staging chunk (k-cols) */
#define NCH (M_DIM / CCH)    /* 32 chunks */

__device__ __forceinline__ u16 f2bf(float f) {
  return __builtin_bit_cast(u16, (__bf16)f);  // HW RNE cvt
}

union Frag {
  bf16x8 f;
  u16 s[8];
  u32x2 h2[2];
  u32x4 q;
};

// zbt layout: ((kt*2 + nt)*64 + lane)*8 + j holds z[k = kt*32 + 8*(lane>>4)+j]
//                                                 [n = nt*16 + (lane&15)]
// Lbt layout: ((rt*256 + ktile)*512) + lane*8 + j holds
//             L[m = rt*16+(lane&15)][k = ktile*32 + 8*(lane>>4) + j]

// ---- head: y_acc = x @ W0 ; zbt0 = frag(bf16(x)) ---------------------------
__global__ __launch_bounds__(256) void head_kernel(
    const float* __restrict__ x, const float* __restrict__ W0,
    float* __restrict__ y_out, u16* __restrict__ zbt0) {
  __shared__ float Ws[1024];
  __shared__ u16 zsb[256][34];
  const int t = threadIdx.x;
  for (int i = t; i < 1024; i += 256) Ws[i] = W0[i];
  const int m = blockIdx.x * 256 + t;
  float z[32];
  const float4* xr = (const float4*)(x + (size_t)m * 32);
#pragma unroll
  for (int i = 0; i < 8; i++) {
    float4 v = xr[i];
    z[4 * i] = v.x; z[4 * i + 1] = v.y; z[4 * i + 2] = v.z; z[4 * i + 3] = v.w;
  }
#pragma unroll
  for (int c = 0; c < 32; c++) zsb[t][c] = f2bf(z[c]);
  __syncthreads();
  float acc[32];
#pragma unroll
  for (int j = 0; j < 32; j++) acc[j] = 0.f;
#pragma unroll
  for (int c = 0; c < 32; c++) {
#pragma unroll
    for (int j = 0; j < 32; j++) acc[j] += z[c] * Ws[c * 32 + j];
  }
  float4* yo = (float4*)(y_out + (size_t)m * 32);
#pragma unroll
  for (int i = 0; i < 8; i++) {
    float4 v; v.x = acc[4 * i]; v.y = acc[4 * i + 1];
    v.z = acc[4 * i + 2]; v.w = acc[4 * i + 3];
    yo[i] = v;
  }
  const int lane = t & 63, w = t >> 6;
  const int l15 = lane & 15, l4 = lane >> 4;
#pragma unroll
  for (int i = 0; i < 4; i++) {
    int tile = w * 4 + i;
    int ktl = tile >> 1, nt = tile & 1;
    Frag fr;
#pragma unroll
    for (int j = 0; j < 8; j++) fr.s[j] = zsb[ktl * 32 + 8 * l4 + j][nt * 16 + l15];
    size_t kt_g = (size_t)blockIdx.x * 8 + ktl;
    *(u32x4*)(zbt0 + ((kt_g * 2 + nt) * 64 + lane) * 8) = fr.q;
  }
}

// ---- conv: L -> Lbt + z1 = L@z0 + y+=z1@W1 + emit zbt1. 4 blocks/CU --------
__global__ __launch_bounds__(512, 8) void conv_kernel(
    const float* __restrict__ L, const u16* __restrict__ zbt0,
    const float* __restrict__ W1, const float* __restrict__ y_in,
    float* __restrict__ y_out, u16* __restrict__ Lbt,
    u16* __restrict__ zbt_out) {
  __shared__ __align__(16) u16 At[2][16][264];  // 16896 B; red overlays after
  __shared__ float Ws[1024];
  __shared__ float zs[16][33];
  __shared__ u16 zsb[16][36];
  float (*red)[16][33] = (float (*)[16][33]) & At[0][0][0];  // 16896 B exact
  const int t = threadIdx.x;
  const int lane = t & 63, w = t >> 6;
  const int l15 = lane & 15, l4 = lane >> 4;
  const int bx = blockIdx.x;  // [0,512) row tile
  const int r0 = bx * 16;
  for (int i = t; i < 1024; i += 512) Ws[i] = W1[i];

  const int srow = t >> 5, scg = t & 31;  // 16 rows x 32 col-groups of 8 f32
  const float* sbase = L + (size_t)(r0 + srow) * M_DIM + scg * 8;

  auto stage = [&](int c, int buf) {
    const float* src = sbase + c * CCH;
    f32x4 v0 = __builtin_nontemporal_load((const f32x4*)src);
    f32x4 v1 = __builtin_nontemporal_load((const f32x4*)(src + 4));
    Frag p;
    p.s[0] = f2bf(v0[0]); p.s[1] = f2bf(v0[1]);
    p.s[2] = f2bf(v0[2]); p.s[3] = f2bf(v0[3]);
    p.s[4] = f2bf(v1[0]); p.s[5] = f2bf(v1[1]);
    p.s[6] = f2bf(v1[2]); p.s[7] = f2bf(v1[3]);
    *(u32x4*)&At[buf][srow][scg * 8] = p.q;
  };

  f32x4 acc0 = {0.f, 0.f, 0.f, 0.f};
  f32x4 acc1 = {0.f, 0.f, 0.f, 0.f};

  stage(0, 0);
  int buf = 0;
  for (int c = 0; c < NCH; c++) {
    __syncthreads();
    if (c + 1 < NCH) stage(c + 1, buf ^ 1);
    // wave w owns k-tile w of this chunk (8 tiles of 32 cols)
    const int ktl = c * 8 + w;  // global k-tile [0,256)
    Frag fa;
    fa.q = *(const u32x4*)&At[buf][l15][w * 32 + 8 * l4];
    *(u32x4*)(Lbt + ((size_t)bx * 256 + ktl) * 512 + lane * 8) = fa.q;
    Frag fb0, fb1;
    size_t bo = ((size_t)ktl * 2) * 512 + lane * 8;
    fb0.q = *(const u32x4*)(zbt0 + bo);
    fb1.q = *(const u32x4*)(zbt0 + bo + 512);
    acc0 = __builtin_amdgcn_mfma_f32_16x16x32_bf16(fa.f, fb0.f, acc0, 0, 0, 0);
    acc1 = __builtin_amdgcn_mfma_f32_16x16x32_bf16(fa.f, fb1.f, acc1, 0, 0, 0);
    buf ^= 1;
  }

  __syncthreads();  // At dead; red overlays it
#pragma unroll
  for (int r = 0; r < 4; r++) {
    red[w][4 * l4 + r][l15] = acc0[r];
    red[w][4 * l4 + r][l15 + 16] = acc1[r];
  }
  __syncthreads();
  const int row = t >> 5, j = t & 31;
  float v = 0.f;
#pragma unroll
  for (int s = 0; s < 8; s++) v += red[s][row][j];
  zs[row][j] = v;
  zsb[row][j] = f2bf(v);
  __syncthreads();
  float yv = y_in[(size_t)(r0 + row) * 32 + j];
#pragma unroll
  for (int c = 0; c < 32; c++) yv += zs[row][c] * Ws[c * 32 + j];
  y_out[(size_t)(r0 + row) * 32 + j] = yv;

  if (t < 64) {
    const int nt = t >> 5, li = t & 31;
    const int kt = bx >> 1, h = bx & 1;
    Frag fr;
#pragma unroll
    for (int jj = 0; jj < 8; jj++)
      fr.s[jj] = zsb[8 * (li >> 4) + jj][nt * 16 + (li & 15)];
    *(u32x4*)(zbt_out + (size_t)((kt * 2 + nt) * 64 + 32 * h + li) * 8) = fr.q;
  }
}

// ---- fpass: z_next = L @ z (full-K, 8-wave K-split), 4 blocks/CU -----------
template <bool LAST>
__global__ __launch_bounds__(512, 8) void fpass_kernel(
    const u16* __restrict__ Lbt, const u16* __restrict__ zbt,
    const float* __restrict__ Wk, const float* __restrict__ y_in,
    float* __restrict__ y_out, u16* __restrict__ zbt_out) {
  __shared__ float red[8][16][33];
  __shared__ float Ws[1024];
  __shared__ float zs[16][33];
  __shared__ u16 zsb[16][36];
  const int t = threadIdx.x;
  const int lane = t & 63, w = t >> 6;
  const int l15 = lane & 15, l4 = lane >> 4;
  const int bx = blockIdx.x;  // [0,512) row tile
  for (int i = t; i < 1024; i += 512) Ws[i] = Wk[i];

  const u16* ap = Lbt + ((size_t)bx * 256 + w * 32) * 512 + lane * 8;
  const u16* bp = zbt + (size_t)(w * 32) * 1024 + lane * 8;

  f32x4 acc0 = {0.f, 0.f, 0.f, 0.f};
  f32x4 acc1 = {0.f, 0.f, 0.f, 0.f};
#pragma unroll 4
  for (int kt = 0; kt < 32; kt++) {
    Frag fa, fb0, fb1;
    fa.q = *(const u32x4*)(ap + (size_t)kt * 512);
    fb0.q = *(const u32x4*)(bp + (size_t)kt * 1024);
    fb1.q = *(const u32x4*)(bp + (size_t)kt * 1024 + 512);
    acc0 = __builtin_amdgcn_mfma_f32_16x16x32_bf16(fa.f, fb0.f, acc0, 0, 0, 0);
    acc1 = __builtin_amdgcn_mfma_f32_16x16x32_bf16(fa.f, fb1.f, acc1, 0, 0, 0);
  }
#pragma unroll
  for (int r = 0; r < 4; r++) {
    red[w][4 * l4 + r][l15] = acc0[r];
    red[w][4 * l4 + r][l15 + 16] = acc1[r];
  }
  __syncthreads();
  const int row = t >> 5, j = t & 31;
  float v = 0.f;
#pragma unroll
  for (int s = 0; s < 8; s++) v += red[s][row][j];
  zs[row][j] = v;
  zsb[row][j] = f2bf(v);
  __syncthreads();
  float yv = y_in[(size_t)(bx * 16 + row) * 32 + j];
#pragma unroll
  for (int c = 0; c < 32; c++) yv += zs[row][c] * Ws[c * 32 + j];
  y_out[(size_t)(bx * 16 + row) * 32 + j] = yv;

  if (!LAST && t < 64) {
    const int nt = t >> 5, li = t & 31;
    const int kt = bx >> 1, h = bx & 1;
    Frag fr;
#pragma unroll
    for (int jj = 0; jj < 8; jj++)
      fr.s[jj] = zsb[8 * (li >> 4) + jj][nt * 16 + (li & 15)];
    *(u32x4*)(zbt_out + (size_t)((kt * 2 + nt) * 64 + 32 * h + li) * 8) = fr.q;
  }
}

extern "C" void kernel_launch(void* const* d_in, const int* in_sizes, int n_in,
                              void* d_out, int out_size, void* d_ws,
                              size_t ws_size, hipStream_t stream) {
  const float* x = (const float*)d_in[0];
  const float* L = (const float*)d_in[1];
  const float* W = (const float*)d_in[2];
  float* y = (float*)d_out;
  char* ws = (char*)d_ws;

  const size_t ZT = (size_t)512 << 10;        // 512 KB per zbt
  u16* zbt0 = (u16*)(ws + 0 * ZT);
  u16* zbt1 = (u16*)(ws + 1 * ZT);
  u16* zbt2 = (u16*)(ws + 2 * ZT);
  u16* zbt3 = (u16*)(ws + 3 * ZT);
  float* y_acc = (float*)(ws + ((size_t)10 << 20));  // 1 MB @ 10 MiB
  u16* Lbt = (u16*)(ws + ((size_t)12 << 20));        // 128 MiB @ 12 MiB

  head_kernel<<<32, 256, 0, stream>>>(x, W, y_acc, zbt0);
  conv_kernel<<<512, 512, 0, stream>>>(L, zbt0, W + 1024, y_acc, y_acc, Lbt, zbt1);
  fpass_kernel<false><<<512, 512, 0, stream>>>(Lbt, zbt1, W + 2048, y_acc, y_acc, zbt2);
  fpass_kernel<false><<<512, 512, 0, stream>>>(Lbt, zbt2, W + 3072, y_acc, y_acc, zbt3);
  fpass_kernel<true><<<512, 512, 0, stream>>>(Lbt, zbt3, W + 4096, y_acc, y, (u16*)0);
}